// Round 5
// baseline (190.130 us; speedup 1.0000x reference)
//
#include <hip/hip_runtime.h>

#define BATCH 4096
#define D_IN 1024
#define D_OUT 1024
#define N_EXPERTS 8

#define TM 64
#define TN 64
#define TK 64
#define MAX_TILES 71   // sum ceil(c_e/64) <= 64 + 7

// ws int32 slots
#define WS_PERM    0       // [4096]
#define WS_STARTS  4096    // [9]
#define WS_TILE_E  4112    // [71]
#define WS_TILE_M  4200    // [71]
#define WS_NTILES  4288    // [1]

typedef __attribute__((ext_vector_type(8))) short short8;   // 8 x bf16
typedef __attribute__((ext_vector_type(4))) float f32x4;

// ---------------------------------------------------------------------------
// Group samples by expert + tile list + fused meta passthrough writes.
// ---------------------------------------------------------------------------
__global__ void group_kernel(const int* __restrict__ actions,
                             const int* __restrict__ mxs,
                             int* __restrict__ ws,
                             float* __restrict__ out, int meta_mode) {
    __shared__ int cnt[N_EXPERTS];
    __shared__ int base[N_EXPERTS];
    const int t = threadIdx.x;
    if (t < N_EXPERTS) cnt[t] = 0;
    __syncthreads();
    const int M = BATCH * D_OUT;
    for (int i = t; i < BATCH; i += 256) {
        const int a = actions[i];
        atomicAdd(&cnt[a], 1);
        if (meta_mode == 1) {
            out[M + i] = (float)mxs[i];
            out[M + BATCH + i] = (float)a;
        } else if (meta_mode == 2) {
            out[M + i] = (float)mxs[i];
            ((long long*)(out + M + BATCH))[i] = (long long)a;
        }
    }
    __syncthreads();
    if (t == 0) {
        int s = 0, nt = 0;
        for (int e = 0; e < N_EXPERTS; ++e) {
            const int c = cnt[e];
            base[e] = s;
            ws[WS_STARTS + e] = s;
            for (int m0 = 0; m0 < c; m0 += TM) {
                ws[WS_TILE_E + nt] = e;
                ws[WS_TILE_M + nt] = m0;
                ++nt;
            }
            s += c;
            cnt[e] = 0;
        }
        ws[WS_STARTS + N_EXPERTS] = s;
        ws[WS_NTILES] = nt;
    }
    __syncthreads();
    for (int i = t; i < BATCH; i += 256) {
        const int a = actions[i];
        const int pos = base[a] + atomicAdd(&cnt[a], 1);
        ws[WS_PERM + pos] = i;
    }
}

// fp32 -> bf16 hi/lo split (truncation; lo captures next 8 mantissa bits)
__device__ __forceinline__ void cvt8(const float4 a, const float4 b,
                                     short8& h, short8& l) {
    float f[8] = {a.x, a.y, a.z, a.w, b.x, b.y, b.z, b.w};
#pragma unroll
    for (int i = 0; i < 8; ++i) {
        const unsigned u = __float_as_uint(f[i]);
        h[i] = (short)(u >> 16);
        const float r = f[i] - __uint_as_float(u & 0xffff0000u);
        l[i] = (short)(__float_as_uint(r) >> 16);
    }
}

// ---------------------------------------------------------------------------
// Split-bf16 MFMA GEMM, 64x64x64 tiles, 1136 blocks -> 4 blocks/CU.
// Thread t stages one 16B fragment-chunk per plane per k-half at LDS offset
// 16*t (thread-linear => conflict-free b128 writes). 4 waves in 2x2 grid,
// each a 32x32 quadrant = 2x2 MFMA tiles x 2 k-halves x 3 MFMA = 24/step.
// ---------------------------------------------------------------------------
__global__ __launch_bounds__(256, 4) void moe_gemm(
    const float* __restrict__ xs, const float* __restrict__ W,
    const float* __restrict__ bias, const int* __restrict__ ws,
    float* __restrict__ out)
{
    // XCD-friendly swizzle: each XCD (id&7) sees 2 n-slabs
    const int nx  = ((blockIdx.x & 7) << 1) | ((blockIdx.x >> 3) & 1);
    const int tix = blockIdx.x >> 4;
    if (tix >= ws[WS_NTILES]) return;
    const int e   = ws[WS_TILE_E + tix];
    const int m0  = ws[WS_TILE_M + tix];
    const int s0  = ws[WS_STARTS + e];
    const int cnt = ws[WS_STARTS + e + 1] - s0;
    const int n0  = nx * TN;

    __shared__ short Ahi[TM * TK];   // 8 KB each plane
    __shared__ short Alo[TM * TK];
    __shared__ short Bhi[TN * TK];
    __shared__ short Blo[TN * TK];
    __shared__ int   rows_s[TM];

    const int t = threadIdx.x;
    if (t < TM) {
        const int r = m0 + t;
        rows_s[t] = (r < cnt) ? ws[WS_PERM + s0 + r] : -1;
    }
    __syncthreads();

    const int lane = t & 63;
    const int wave = t >> 6;
    const int wm = (wave & 1) * 32;
    const int wn = (wave >> 1) * 32;

    const float zf = 0.f;
    f32x4 acc[2][2];
#pragma unroll
    for (int mi = 0; mi < 2; ++mi)
#pragma unroll
        for (int nj = 0; nj < 2; ++nj)
            acc[mi][nj] = (f32x4){zf, zf, zf, zf};

    // Staging role: thread t owns fragment chunk (t&63) of m-tile (t>>6),
    // i.e. row_l = (t>>6)*16 + (t&15), k-octet kq = (t>>4)&3, for both k-halves.
    const int li = t & 15;
    const int kq = (t >> 4) & 3;
    const int row_l = (t >> 6) * 16 + li;
    const int arow = rows_s[row_l];
    const float* ap = xs + (size_t)((arow < 0) ? 0 : arow) * D_IN + kq * 8;
    const float* bp = W + ((size_t)e << 20) + (size_t)(n0 + row_l) * D_IN + kq * 8;
    const int st = t * 8;   // short offset of this thread's chunk (k-half 0)

    for (int k0 = 0; k0 < D_IN; k0 += TK) {
        __syncthreads();
#pragma unroll
        for (int kt = 0; kt < 2; ++kt) {
            const float4 a0 = *(const float4*)(ap + k0 + kt * 32);
            const float4 a1 = *(const float4*)(ap + k0 + kt * 32 + 4);
            short8 h, l;
            cvt8(a0, a1, h, l);
            *(short8*)&Ahi[kt * 2048 + st] = h;
            *(short8*)&Alo[kt * 2048 + st] = l;
            const float4 b0 = *(const float4*)(bp + k0 + kt * 32);
            const float4 b1 = *(const float4*)(bp + k0 + kt * 32 + 4);
            cvt8(b0, b1, h, l);
            *(short8*)&Bhi[kt * 2048 + st] = h;
            *(short8*)&Blo[kt * 2048 + st] = l;
        }
        __syncthreads();

#pragma unroll
        for (int kt = 0; kt < 2; ++kt) {
            short8 ah[2], al[2], bh[2], bl[2];
#pragma unroll
            for (int i2 = 0; i2 < 2; ++i2) {
                const int aoff = kt * 2048 + ((wm >> 4) + i2) * 512 + lane * 8;
                ah[i2] = *(const short8*)&Ahi[aoff];
                al[i2] = *(const short8*)&Alo[aoff];
                const int boff = kt * 2048 + ((wn >> 4) + i2) * 512 + lane * 8;
                bh[i2] = *(const short8*)&Bhi[boff];
                bl[i2] = *(const short8*)&Blo[boff];
            }
#pragma unroll
            for (int mi = 0; mi < 2; ++mi)
#pragma unroll
                for (int nj = 0; nj < 2; ++nj) {
                    acc[mi][nj] = __builtin_amdgcn_mfma_f32_16x16x32_bf16(ah[mi], bh[nj], acc[mi][nj], 0, 0, 0);
                    acc[mi][nj] = __builtin_amdgcn_mfma_f32_16x16x32_bf16(ah[mi], bl[nj], acc[mi][nj], 0, 0, 0);
                    acc[mi][nj] = __builtin_amdgcn_mfma_f32_16x16x32_bf16(al[mi], bh[nj], acc[mi][nj], 0, 0, 0);
                }
        }
    }

    // Epilogue (verified layout): col=lane&15, row=(lane>>4)*4+reg
    const int cl = lane & 15;
    const int qd = lane >> 4;
    float bv[2];
#pragma unroll
    for (int nj = 0; nj < 2; ++nj)
        bv[nj] = bias[e * D_OUT + n0 + wn + nj * 16 + cl];
#pragma unroll
    for (int mi = 0; mi < 2; ++mi) {
#pragma unroll
        for (int reg = 0; reg < 4; ++reg) {
            const int mloc = wm + mi * 16 + qd * 4 + reg;
            const int r = rows_s[mloc];
            if (r >= 0) {
                float* orow = out + (size_t)r * D_OUT + n0 + wn + cl;
#pragma unroll
                for (int nj = 0; nj < 2; ++nj)
                    orow[nj * 16] = acc[mi][nj][reg] + bv[nj];
            }
        }
    }
}

extern "C" void kernel_launch(void* const* d_in, const int* in_sizes, int n_in,
                              void* d_out, int out_size, void* d_ws, size_t ws_size,
                              hipStream_t stream) {
    const float* xs      = (const float*)d_in[0];
    const int*   mxs     = (const int*)d_in[1];
    const int*   actions = (const int*)d_in[2];
    const float* W       = (const float*)d_in[3];
    const float* bias    = (const float*)d_in[4];
    float* out = (float*)d_out;
    int*   ws  = (int*)d_ws;

    const int metaOff = BATCH * D_OUT;
    int meta_mode = 0;
    if (out_size >= metaOff + 3 * BATCH) meta_mode = 2;
    else if (out_size >= metaOff + 2 * BATCH) meta_mode = 1;

    group_kernel<<<1, 256, 0, stream>>>(actions, mxs, ws, out, meta_mode);

    moe_gemm<<<16 * MAX_TILES, 256, 0, stream>>>(xs, W, bias, ws, out);
}

// Round 6
// 159.967 us; speedup vs baseline: 1.1886x; 1.1886x over previous
//
#include <hip/hip_runtime.h>

#define BATCH 4096
#define D_IN 1024
#define D_OUT 1024
#define N_EXPERTS 8

#define TM 64
#define TN 128
#define TK 32
#define MAX_TILES 71   // sum ceil(c_e/64) <= 64 + 7

// ws int32 slots
#define WS_PERM    0       // [4096]
#define WS_STARTS  4096    // [9]
#define WS_TILE_E  4112    // [71]
#define WS_TILE_M  4200    // [71]
#define WS_NTILES  4288    // [1]

typedef __attribute__((ext_vector_type(8))) short short8;   // 8 x bf16
typedef __attribute__((ext_vector_type(4))) float f32x4;

// ---------------------------------------------------------------------------
// Atomic-free grouping: per-thread register histograms (16 elems/thread),
// Hillis-Steele scan over the 256 thread-hists in LDS, stable direct scatter.
// Meta passthrough fused. One block, ~3-5 us (replaces ~80 us atomic storm).
// ---------------------------------------------------------------------------
__global__ __launch_bounds__(256) void group_kernel(
    const int* __restrict__ actions, const int* __restrict__ mxs,
    int* __restrict__ ws, float* __restrict__ out, int meta_mode) {
    __shared__ int h[256][N_EXPERTS];      // inclusive-scanned thread hists
    __shared__ int starts_s[N_EXPERTS];

    const int t = threadIdx.x;
    const int i0 = t * 16;
    int a_loc[16];
    int lc[N_EXPERTS];
#pragma unroll
    for (int e = 0; e < N_EXPERTS; ++e) lc[e] = 0;

    const int M = BATCH * D_OUT;
#pragma unroll
    for (int i = 0; i < 16; ++i) {
        const int a = actions[i0 + i];
        a_loc[i] = a;
        ++lc[a];
        if (meta_mode == 1) {
            out[M + i0 + i] = (float)mxs[i0 + i];
            out[M + BATCH + i0 + i] = (float)a;
        } else if (meta_mode == 2) {
            out[M + i0 + i] = (float)mxs[i0 + i];
            ((long long*)(out + M + BATCH))[i0 + i] = (long long)a;
        }
    }
#pragma unroll
    for (int e = 0; e < N_EXPERTS; ++e) h[t][e] = lc[e];
    __syncthreads();

    // inclusive scan over threads (vector of 8 per thread)
    for (int d = 1; d < 256; d <<= 1) {
        int v[N_EXPERTS];
        const bool act = (t >= d);
        if (act) {
#pragma unroll
            for (int e = 0; e < N_EXPERTS; ++e) v[e] = h[t - d][e];
        }
        __syncthreads();
        if (act) {
#pragma unroll
            for (int e = 0; e < N_EXPERTS; ++e) h[t][e] += v[e];
        }
        __syncthreads();
    }

    if (t == 0) {
        int s = 0, nt = 0;
        for (int e = 0; e < N_EXPERTS; ++e) {
            const int c = h[255][e];       // total count for expert e
            starts_s[e] = s;
            ws[WS_STARTS + e] = s;
            for (int m0 = 0; m0 < c; m0 += TM) {
                ws[WS_TILE_E + nt] = e;
                ws[WS_TILE_M + nt] = m0;
                ++nt;
            }
            s += c;
        }
        ws[WS_STARTS + N_EXPERTS] = s;
        ws[WS_NTILES] = nt;
    }
    __syncthreads();

    int off[N_EXPERTS];
#pragma unroll
    for (int e = 0; e < N_EXPERTS; ++e)
        off[e] = starts_s[e] + h[t][e] - lc[e];   // exclusive prefix for this thread
#pragma unroll
    for (int i = 0; i < 16; ++i) {
        const int a = a_loc[i];
        ws[WS_PERM + off[a]] = i0 + i;
        ++off[a];
    }
}

// fp32 -> bf16 hi/lo split (truncation; lo captures next 8 mantissa bits)
__device__ __forceinline__ void cvt8(const float4 a, const float4 b,
                                     short8& h, short8& l) {
    float f[8] = {a.x, a.y, a.z, a.w, b.x, b.y, b.z, b.w};
#pragma unroll
    for (int i = 0; i < 8; ++i) {
        const unsigned u = __float_as_uint(f[i]);
        h[i] = (short)(u >> 16);
        const float r = f[i] - __uint_as_float(u & 0xffff0000u);
        l[i] = (short)(__float_as_uint(r) >> 16);
    }
}

// ---------------------------------------------------------------------------
// Split-bf16 MFMA GEMM (R2 config, best measured: 72 us).
// TM=64 x TN=128 / block; 4 waves in 2x2 grid, each a 32x64 quadrant as a
// 2x4 grid of 16x16x32 MFMA tiles, 3 MFMA per tile (hi*hi + hi*lo + lo*hi).
// ---------------------------------------------------------------------------
__global__ __launch_bounds__(256) void moe_gemm(
    const float* __restrict__ xs, const float* __restrict__ W,
    const float* __restrict__ bias, const int* __restrict__ ws,
    float* __restrict__ out)
{
    const int tix = blockIdx.y;
    if (tix >= ws[WS_NTILES]) return;
    const int e   = ws[WS_TILE_E + tix];
    const int m0  = ws[WS_TILE_M + tix];
    const int s0  = ws[WS_STARTS + e];
    const int cnt = ws[WS_STARTS + e + 1] - s0;
    const int n0  = blockIdx.x * TN;

    __shared__ short Ahi[TM * TK];
    __shared__ short Alo[TM * TK];
    __shared__ short Bhi[TN * TK];
    __shared__ short Blo[TN * TK];
    __shared__ int   rows_s[TM];

    const int t = threadIdx.x;
    if (t < TM) {
        const int r = m0 + t;
        rows_s[t] = (r < cnt) ? ws[WS_PERM + s0 + r] : -1;
    }
    __syncthreads();

    const int lane = t & 63;
    const int wave = t >> 6;
    const int wm = (wave & 1) * 32;
    const int wn = (wave >> 1) * 64;

    const float zf = 0.f;
    f32x4 acc[2][4];
#pragma unroll
    for (int mi = 0; mi < 2; ++mi)
#pragma unroll
        for (int nj = 0; nj < 4; ++nj)
            acc[mi][nj] = (f32x4){zf, zf, zf, zf};

    const float* Wb = W + (size_t)e * (D_OUT * (size_t)D_IN) + (size_t)n0 * D_IN;
    const int j  = t & 3;
    const int rr = t >> 2;
    const int arow = rows_s[rr];
    const float* aptr = (arow >= 0) ? (xs + (size_t)arow * D_IN + j * 8) : nullptr;
    const int aoff_st = (rr >> 4) * 512 + (j * 16 + (rr & 15)) * 8;

    for (int k0 = 0; k0 < D_IN; k0 += TK) {
        __syncthreads();
        {
            float4 v0 = make_float4(0.f, 0.f, 0.f, 0.f), v1 = v0;
            if (aptr) {
                v0 = *(const float4*)(aptr + k0);
                v1 = *(const float4*)(aptr + k0 + 4);
            }
            short8 h, l;
            cvt8(v0, v1, h, l);
            *(short8*)&Ahi[aoff_st] = h;
            *(short8*)&Alo[aoff_st] = l;
        }
#pragma unroll
        for (int i = 0; i < 2; ++i) {
            const int n   = i * 64 + rr;
            const int off = (n >> 4) * 512 + (j * 16 + (n & 15)) * 8;
            const float* q = Wb + (size_t)n * D_IN + k0 + j * 8;
            const float4 w0 = *(const float4*)q;
            const float4 w1 = *(const float4*)(q + 4);
            short8 h, l;
            cvt8(w0, w1, h, l);
            *(short8*)&Bhi[off] = h;
            *(short8*)&Blo[off] = l;
        }
        __syncthreads();

        short8 ah[2], al[2], bh[4], bl[4];
#pragma unroll
        for (int i2 = 0; i2 < 2; ++i2) {
            const int aoff = ((wm >> 4) + i2) * 512 + lane * 8;
            ah[i2] = *(const short8*)&Ahi[aoff];
            al[i2] = *(const short8*)&Alo[aoff];
        }
#pragma unroll
        for (int i2 = 0; i2 < 4; ++i2) {
            const int boff = ((wn >> 4) + i2) * 512 + lane * 8;
            bh[i2] = *(const short8*)&Bhi[boff];
            bl[i2] = *(const short8*)&Blo[boff];
        }
#pragma unroll
        for (int mi = 0; mi < 2; ++mi)
#pragma unroll
            for (int nj = 0; nj < 4; ++nj) {
                acc[mi][nj] = __builtin_amdgcn_mfma_f32_16x16x32_bf16(ah[mi], bh[nj], acc[mi][nj], 0, 0, 0);
                acc[mi][nj] = __builtin_amdgcn_mfma_f32_16x16x32_bf16(ah[mi], bl[nj], acc[mi][nj], 0, 0, 0);
                acc[mi][nj] = __builtin_amdgcn_mfma_f32_16x16x32_bf16(al[mi], bh[nj], acc[mi][nj], 0, 0, 0);
            }
    }

    // Epilogue (verified layout): col=lane&15, row=(lane>>4)*4+reg
    const int cl = lane & 15;
    const int qd = lane >> 4;
    float bv[4];
#pragma unroll
    for (int nj = 0; nj < 4; ++nj)
        bv[nj] = bias[e * D_OUT + n0 + wn + nj * 16 + cl];
#pragma unroll
    for (int mi = 0; mi < 2; ++mi) {
#pragma unroll
        for (int reg = 0; reg < 4; ++reg) {
            const int mloc = wm + mi * 16 + qd * 4 + reg;
            const int r = rows_s[mloc];
            if (r >= 0) {
                float* orow = out + (size_t)r * D_OUT + n0 + wn + cl;
#pragma unroll
                for (int nj = 0; nj < 4; ++nj)
                    orow[nj * 16] = acc[mi][nj][reg] + bv[nj];
            }
        }
    }
}

extern "C" void kernel_launch(void* const* d_in, const int* in_sizes, int n_in,
                              void* d_out, int out_size, void* d_ws, size_t ws_size,
                              hipStream_t stream) {
    const float* xs      = (const float*)d_in[0];
    const int*   mxs     = (const int*)d_in[1];
    const int*   actions = (const int*)d_in[2];
    const float* W       = (const float*)d_in[3];
    const float* bias    = (const float*)d_in[4];
    float* out = (float*)d_out;
    int*   ws  = (int*)d_ws;

    const int metaOff = BATCH * D_OUT;
    int meta_mode = 0;
    if (out_size >= metaOff + 3 * BATCH) meta_mode = 2;
    else if (out_size >= metaOff + 2 * BATCH) meta_mode = 1;

    group_kernel<<<1, 256, 0, stream>>>(actions, mxs, ws, out, meta_mode);

    dim3 grid(D_OUT / TN, MAX_TILES, 1);
    moe_gemm<<<grid, 256, 0, stream>>>(xs, W, bias, ws, out);
}